// Round 1
// baseline (923.308 us; speedup 1.0000x reference)
//
#include <hip/hip_runtime.h>
#include <math.h>

#define IN_F 128
#define C_TOT 256   // OUT*H
#define NEG_SLOPE 0.2f

// ---------------- GEMM: Zp = Z @ W^T + b  (f32, LDS-tiled) ----------------
// block: 256 threads; tile: 32 rows x 256 cols; K=128 in 4 chunks of 32.
// W chunk staged with XOR swizzle (float4 granularity) -> conflict-free reads.
__global__ __launch_bounds__(256) void gemm_kernel(
    const float* __restrict__ Z, const float* __restrict__ W,
    const float* __restrict__ b, float* __restrict__ Zp, int N)
{
    __shared__ float4 Z4s[32 * 32];   // [r][k4], 16 KB
    __shared__ float4 W4s[256 * 8];   // per-chunk [c][k4^swz], 32 KB
    const int t    = threadIdx.x;
    const int c2   = t & 127;         // column 0..127 (also owns c2+128)
    const int half = t >> 7;          // row half 0/1
    const int n0   = blockIdx.x * 32;

    // stage Z tile (guarded)
    for (int j = 0; j < 4; ++j) {
        int f4 = j * 256 + t;
        int r = f4 >> 5, k4 = f4 & 31;
        int gr = n0 + r;
        float4 v = make_float4(0.f, 0.f, 0.f, 0.f);
        if (gr < N) v = *(const float4*)&Z[(size_t)gr * IN_F + k4 * 4];
        Z4s[r * 32 + k4] = v;
    }

    float acc0[16], acc1[16];
#pragma unroll
    for (int r = 0; r < 16; ++r) { acc0[r] = 0.f; acc1[r] = 0.f; }

    for (int kc = 0; kc < 4; ++kc) {
        __syncthreads();   // Z staged / previous chunk consumed
        // stage W[:, kc*32 .. kc*32+31]
        for (int j = 0; j < 8; ++j) {
            int f4 = j * 256 + t;
            int c = f4 >> 3, k4 = f4 & 7;
            float4 v = *(const float4*)&W[(size_t)c * IN_F + kc * 32 + k4 * 4];
            W4s[c * 8 + (k4 ^ (c & 7))] = v;
        }
        __syncthreads();
#pragma unroll
        for (int k4 = 0; k4 < 8; ++k4) {
            float4 wa = W4s[c2 * 8 + (k4 ^ (c2 & 7))];
            float4 wb = W4s[(c2 + 128) * 8 + (k4 ^ (c2 & 7))];
#pragma unroll
            for (int r = 0; r < 16; ++r) {
                float4 z = Z4s[(half * 16 + r) * 32 + kc * 8 + k4];  // wave-uniform broadcast
                acc0[r] += wa.x * z.x + wa.y * z.y + wa.z * z.z + wa.w * z.w;
                acc1[r] += wb.x * z.x + wb.y * z.y + wb.z * z.z + wb.w * z.w;
            }
        }
    }
    float bA = b[c2], bB = b[c2 + 128];
    for (int r = 0; r < 16; ++r) {
        int gr = n0 + half * 16 + r;
        if (gr < N) {
            Zp[(size_t)gr * C_TOT + c2]       = acc0[r] + bA;
            Zp[(size_t)gr * C_TOT + c2 + 128] = acc1[r] + bB;
        }
    }
}

// ---------------- per-node attention logits e_l, e_r ----------------
// one wave per node: lane reads Zp[n, lane*4 .. +3], dot with a_l/a_r, shfl-reduce
__global__ __launch_bounds__(256) void elr_kernel(
    const float* __restrict__ Zp, const float* __restrict__ a_l,
    const float* __restrict__ a_r, float* __restrict__ el,
    float* __restrict__ er, int N)
{
    int wave = threadIdx.x >> 6, lane = threadIdx.x & 63;
    int n = blockIdx.x * 4 + wave;
    if (n >= N) return;
    float4 z  = *(const float4*)&Zp[(size_t)n * C_TOT + lane * 4];
    float4 al = *(const float4*)&a_l[lane * 4];
    float4 ar = *(const float4*)&a_r[lane * 4];
    float4 pl, pr;
    pl.x = z.x * al.x; pl.y = z.y * al.y; pl.z = z.z * al.z; pl.w = z.w * al.w;
    pr.x = z.x * ar.x; pr.y = z.y * ar.y; pr.z = z.z * ar.z; pr.w = z.w * ar.w;
    for (int d = 1; d < 64; d <<= 1) {
        pl.x += __shfl_xor(pl.x, d); pl.y += __shfl_xor(pl.y, d);
        pl.z += __shfl_xor(pl.z, d); pl.w += __shfl_xor(pl.w, d);
        pr.x += __shfl_xor(pr.x, d); pr.y += __shfl_xor(pr.y, d);
        pr.z += __shfl_xor(pr.z, d); pr.w += __shfl_xor(pr.w, d);
    }
    if (lane == 0) {
        *(float4*)&el[(size_t)n * 4] = pl;
        *(float4*)&er[(size_t)n * 4] = pr;
    }
}

// ---------------- CSR build ----------------
__global__ void hist_kernel(const int* __restrict__ row, int* __restrict__ cur, int E)
{
    int e = blockIdx.x * blockDim.x + threadIdx.x;
    if (e < E) atomicAdd(&cur[row[e]], 1);
}

__global__ __launch_bounds__(1024) void scan_kernel(
    const int* __restrict__ cnt, int* __restrict__ off, int N)
{
    __shared__ int sums[1024];
    int tid = threadIdx.x;
    int chunk = (N + 1023) >> 10;
    int beg = tid * chunk;
    int end = beg + chunk; if (end > N) end = N;
    int s = 0;
    for (int i = beg; i < end; ++i) s += cnt[i];
    sums[tid] = s;
    __syncthreads();
    for (int d = 1; d < 1024; d <<= 1) {
        int v = (tid >= d) ? sums[tid - d] : 0;
        __syncthreads();
        sums[tid] += v;
        __syncthreads();
    }
    int run = tid ? sums[tid - 1] : 0;
    for (int i = beg; i < end; ++i) { off[i] = run; run += cnt[i]; }
    if (tid == 1023) off[N] = sums[1023];
}

__global__ void scatter_kernel(const int* __restrict__ row, const int* __restrict__ col,
                               int* __restrict__ cur, int* __restrict__ ebuf, int E)
{
    int e = blockIdx.x * blockDim.x + threadIdx.x;
    if (e < E) {
        int r = row[e];
        int pos = atomicAdd(&cur[r], 1);
        ebuf[pos] = col[e];   // store the source node directly; edge id never needed
    }
}

// ---------------- fused segment softmax + aggregation ----------------
// one wave per destination node. Pass 1: exact segment max. Pass 2: accumulate
// unnormalized sum_e w_e * Zp[col_e] in registers (lane owns feats lane*4..+3,
// h = feat&3), plus denominator; single scale at the end. No float atomics.
__global__ __launch_bounds__(256) void node_kernel(
    const int* __restrict__ off, const int* __restrict__ ebuf,
    const float* __restrict__ el, const float* __restrict__ er,
    const float* __restrict__ Zp, float* __restrict__ out, int N)
{
    int wave = threadIdx.x >> 6, lane = threadIdx.x & 63;
    int n = blockIdx.x * 4 + wave;
    if (n >= N) return;
    int beg = off[n], end = off[n + 1];
    float4 el4 = *(const float4*)&el[(size_t)n * 4];

    // pass 1: segment max per head
    float mx0 = -INFINITY, mx1 = -INFINITY, mx2 = -INFINITY, mx3 = -INFINITY;
    for (int i = beg + lane; i < end; i += 64) {
        int c = ebuf[i];
        float4 er4 = *(const float4*)&er[(size_t)c * 4];
        float a0 = el4.x + er4.x; a0 = a0 > 0.f ? a0 : NEG_SLOPE * a0;
        float a1 = el4.y + er4.y; a1 = a1 > 0.f ? a1 : NEG_SLOPE * a1;
        float a2 = el4.z + er4.z; a2 = a2 > 0.f ? a2 : NEG_SLOPE * a2;
        float a3 = el4.w + er4.w; a3 = a3 > 0.f ? a3 : NEG_SLOPE * a3;
        mx0 = fmaxf(mx0, a0); mx1 = fmaxf(mx1, a1);
        mx2 = fmaxf(mx2, a2); mx3 = fmaxf(mx3, a3);
    }
    for (int d = 1; d < 64; d <<= 1) {
        mx0 = fmaxf(mx0, __shfl_xor(mx0, d));
        mx1 = fmaxf(mx1, __shfl_xor(mx1, d));
        mx2 = fmaxf(mx2, __shfl_xor(mx2, d));
        mx3 = fmaxf(mx3, __shfl_xor(mx3, d));
    }

    // pass 2: weighted accumulation, chunks of 64 edges
    float acc0 = 0.f, acc1 = 0.f, acc2 = 0.f, acc3 = 0.f;
    float ds0 = 0.f, ds1 = 0.f, ds2 = 0.f, ds3 = 0.f;
    for (int base = beg; base < end; base += 64) {
        int i = base + lane;
        int cnt = end - base; if (cnt > 64) cnt = 64;
        int c = 0;
        float w0 = 0.f, w1 = 0.f, w2 = 0.f, w3 = 0.f;
        if (i < end) {
            c = ebuf[i];
            float4 er4 = *(const float4*)&er[(size_t)c * 4];
            float a0 = el4.x + er4.x; a0 = a0 > 0.f ? a0 : NEG_SLOPE * a0;
            float a1 = el4.y + er4.y; a1 = a1 > 0.f ? a1 : NEG_SLOPE * a1;
            float a2 = el4.z + er4.z; a2 = a2 > 0.f ? a2 : NEG_SLOPE * a2;
            float a3 = el4.w + er4.w; a3 = a3 > 0.f ? a3 : NEG_SLOPE * a3;
            w0 = __expf(a0 - mx0); w1 = __expf(a1 - mx1);
            w2 = __expf(a2 - mx2); w3 = __expf(a3 - mx3);
            ds0 += w0; ds1 += w1; ds2 += w2; ds3 += w3;
        }
        for (int j = 0; j < cnt; ++j) {
            int cc = __shfl(c, j);
            float vw0 = __shfl(w0, j);
            float vw1 = __shfl(w1, j);
            float vw2 = __shfl(w2, j);
            float vw3 = __shfl(w3, j);
            float4 z = *(const float4*)&Zp[(size_t)cc * C_TOT + lane * 4];
            acc0 += vw0 * z.x; acc1 += vw1 * z.y;
            acc2 += vw2 * z.z; acc3 += vw3 * z.w;
        }
    }
    for (int d = 1; d < 64; d <<= 1) {
        ds0 += __shfl_xor(ds0, d); ds1 += __shfl_xor(ds1, d);
        ds2 += __shfl_xor(ds2, d); ds3 += __shfl_xor(ds3, d);
    }
    float i0 = ds0 > 0.f ? 1.f / ds0 : 1.f;
    float i1 = ds1 > 0.f ? 1.f / ds1 : 1.f;
    float i2 = ds2 > 0.f ? 1.f / ds2 : 1.f;
    float i3 = ds3 > 0.f ? 1.f / ds3 : 1.f;
    float4 o;
    o.x = acc0 * i0; o.y = acc1 * i1; o.z = acc2 * i2; o.w = acc3 * i3;
    *(float4*)&out[(size_t)n * C_TOT + lane * 4] = o;
}

extern "C" void kernel_launch(void* const* d_in, const int* in_sizes, int n_in,
                              void* d_out, int out_size, void* d_ws, size_t ws_size,
                              hipStream_t stream)
{
    const float* Z   = (const float*)d_in[0];
    const int*   row = (const int*)d_in[1];
    const int*   col = (const int*)d_in[2];
    const float* W   = (const float*)d_in[3];
    const float* b   = (const float*)d_in[4];
    const float* a_l = (const float*)d_in[5];
    const float* a_r = (const float*)d_in[6];
    float* out = (float*)d_out;
    const int N = in_sizes[0] / IN_F;
    const int E = in_sizes[1];

    // workspace layout (≈113 MB total)
    char* ws = (char*)d_ws;
    size_t o = 0;
    auto alloc = [&](size_t bytes) -> void* {
        void* p = ws + o;
        o = (o + bytes + 255) & ~(size_t)255;
        return p;
    };
    float* Zp   = (float*)alloc((size_t)N * C_TOT * 4);
    float* el   = (float*)alloc((size_t)N * 4 * 4);
    float* er   = (float*)alloc((size_t)N * 4 * 4);
    int*   off  = (int*)alloc((size_t)(N + 1) * 4);
    int*   cur  = (int*)alloc((size_t)N * 4);
    int*   ebuf = (int*)alloc((size_t)E * 4);

    // CSR build (by destination = row)
    hipMemsetAsync(cur, 0, (size_t)N * 4, stream);
    hist_kernel<<<(E + 255) / 256, 256, 0, stream>>>(row, cur, E);
    scan_kernel<<<1, 1024, 0, stream>>>(cur, off, N);
    hipMemcpyAsync(cur, off, (size_t)N * 4, hipMemcpyDeviceToDevice, stream);
    scatter_kernel<<<(E + 255) / 256, 256, 0, stream>>>(row, col, cur, ebuf, E);

    // projection + logits
    gemm_kernel<<<(N + 31) / 32, 256, 0, stream>>>(Z, W, b, Zp, N);
    elr_kernel<<<(N + 3) / 4, 256, 0, stream>>>(Zp, a_l, a_r, el, er, N);

    // fused softmax + aggregation
    node_kernel<<<(N + 3) / 4, 256, 0, stream>>>(off, ebuf, el, er, Zp, out, N);
}

// Round 2
// 591.730 us; speedup vs baseline: 1.5604x; 1.5604x over previous
//
#include <hip/hip_runtime.h>
#include <math.h>

#define IN_F 128
#define C_TOT 256   // OUT*H
#define NEG_SLOPE 0.2f

typedef __attribute__((ext_vector_type(8))) short short8;
typedef __attribute__((ext_vector_type(4))) float f32x4;

static __device__ __forceinline__ ushort f2bf(float f) {
    unsigned u = __float_as_uint(f);
    unsigned r = (u + 0x7FFF + ((u >> 16) & 1)) >> 16;   // RNE
    return (ushort)r;
}

// ---------------- f32 -> bf16 conversion (vectorized, grid-stride) ----------
__global__ __launch_bounds__(256) void cvt_kernel(const float* __restrict__ src,
                                                  ushort* __restrict__ dst, int n4)
{
    int i = blockIdx.x * blockDim.x + threadIdx.x;
    int stride = gridDim.x * blockDim.x;
    for (; i < n4; i += stride) {
        float4 v = *(const float4*)&src[(size_t)i * 4];
        ushort4 o;
        o.x = f2bf(v.x); o.y = f2bf(v.y); o.z = f2bf(v.z); o.w = f2bf(v.w);
        *(ushort4*)&dst[(size_t)i * 4] = o;
    }
}

// ---------------- MFMA GEMM: Zp = Z @ W^T + b (bf16 in, bf16 out) ----------
// One wave per 16-row tile; wave covers all 256 cols (16 col-tiles of 16).
// A/B fragments loaded directly from global with the SAME (lq,j)->k mapping,
// so the K-contraction is correct for any internal k-permutation.
// Fused epilogue: bias add, bf16 Zp store, e_l/e_r row dots.
__global__ __launch_bounds__(256) void gemm_mfma_kernel(
    const ushort* __restrict__ Zb, const ushort* __restrict__ Wb,
    const float* __restrict__ bias, const float* __restrict__ a_l,
    const float* __restrict__ a_r, ushort* __restrict__ Zp,
    float* __restrict__ el, float* __restrict__ er, int N)
{
    const int wave = threadIdx.x >> 6, lane = threadIdx.x & 63;
    const int lr = lane & 15, lq = lane >> 4;
    const int row0 = (blockIdx.x * 4 + wave) * 16;
    if (row0 >= N) return;

    short8 afrag[4];
    const bool rowok = (row0 + lr) < N;
    const short* zrow = (const short*)Zb + (size_t)(row0 + lr) * IN_F + lq * 8;
#pragma unroll
    for (int ks = 0; ks < 4; ++ks)
        afrag[ks] = rowok ? *(const short8*)(zrow + ks * 32) : (short8)0;

    f32x4 acc[16];
#pragma unroll
    for (int ct = 0; ct < 16; ++ct) acc[ct] = (f32x4)0.f;

#pragma unroll
    for (int ks = 0; ks < 4; ++ks) {
#pragma unroll
        for (int ct = 0; ct < 16; ++ct) {
            short8 bfrag = *(const short8*)((const short*)Wb +
                           (size_t)(ct * 16 + lr) * IN_F + ks * 32 + lq * 8);
            acc[ct] = __builtin_amdgcn_mfma_f32_16x16x32_bf16(afrag[ks], bfrag, acc[ct], 0, 0, 0);
        }
    }

    // epilogue: D layout col = lane&15, row = (lane>>4)*4 + reg  [verified m89]
    float elp[4] = {0.f, 0.f, 0.f, 0.f}, erp[4] = {0.f, 0.f, 0.f, 0.f};
#pragma unroll
    for (int ct = 0; ct < 16; ++ct) {
        const int col = ct * 16 + lr;
        const float bb = bias[col];
        const float al = a_l[col];
        const float ar = a_r[col];
#pragma unroll
        for (int r = 0; r < 4; ++r) {
            const int row = row0 + lq * 4 + r;
            float v = acc[ct][r] + bb;
            if (row < N) Zp[(size_t)row * C_TOT + col] = f2bf(v);
            elp[r] += v * al;
            erp[r] += v * ar;
        }
    }
    // complete the col-sum per head: reduce over lane bits 2,3 (lr ^ 4, ^ 8)
#pragma unroll
    for (int r = 0; r < 4; ++r) {
        elp[r] += __shfl_xor(elp[r], 4); elp[r] += __shfl_xor(elp[r], 8);
        erp[r] += __shfl_xor(erp[r], 4); erp[r] += __shfl_xor(erp[r], 8);
    }
    if (lr < 4) {   // lane lr holds head h = lr for rows row0 + lq*4 + r
#pragma unroll
        for (int r = 0; r < 4; ++r) {
            const int row = row0 + lq * 4 + r;
            if (row < N) {
                el[row * 4 + lr] = elp[r];
                er[row * 4 + lr] = erp[r];
            }
        }
    }
}

// ---------------- CSR build ----------------
__global__ void hist_kernel(const int* __restrict__ row, int* __restrict__ cur, int E)
{
    int e = blockIdx.x * blockDim.x + threadIdx.x;
    if (e < E) atomicAdd(&cur[row[e]], 1);
}

__global__ __launch_bounds__(1024) void scan_kernel(
    const int* __restrict__ cnt, int* __restrict__ off, int N)
{
    __shared__ int sums[1024];
    int tid = threadIdx.x;
    int chunk = (N + 1023) >> 10;
    int beg = tid * chunk;
    int end = beg + chunk; if (end > N) end = N;
    int s = 0;
    for (int i = beg; i < end; ++i) s += cnt[i];
    sums[tid] = s;
    __syncthreads();
    for (int d = 1; d < 1024; d <<= 1) {
        int v = (tid >= d) ? sums[tid - d] : 0;
        __syncthreads();
        sums[tid] += v;
        __syncthreads();
    }
    int run = tid ? sums[tid - 1] : 0;
    for (int i = beg; i < end; ++i) { off[i] = run; run += cnt[i]; }
    if (tid == 1023) off[N] = sums[1023];
}

__global__ void scatter_kernel(const int* __restrict__ row, const int* __restrict__ col,
                               int* __restrict__ cur, int* __restrict__ ebuf, int E)
{
    int e = blockIdx.x * blockDim.x + threadIdx.x;
    if (e < E) {
        int r = row[e];
        int pos = atomicAdd(&cur[r], 1);
        ebuf[pos] = col[e];
    }
}

// ---------------- fused segment softmax + aggregation (bf16 Zp gathers) -----
__global__ __launch_bounds__(256) void node_kernel(
    const int* __restrict__ off, const int* __restrict__ ebuf,
    const float* __restrict__ el, const float* __restrict__ er,
    const ushort* __restrict__ Zp, float* __restrict__ out, int N)
{
    int wave = threadIdx.x >> 6, lane = threadIdx.x & 63;
    int n = blockIdx.x * 4 + wave;
    if (n >= N) return;
    int beg = off[n], end = off[n + 1];
    float4 el4 = *(const float4*)&el[(size_t)n * 4];

    // pass 1: exact segment max per head
    float mx0 = -INFINITY, mx1 = -INFINITY, mx2 = -INFINITY, mx3 = -INFINITY;
    for (int i = beg + lane; i < end; i += 64) {
        int c = ebuf[i];
        float4 er4 = *(const float4*)&er[(size_t)c * 4];
        float a0 = el4.x + er4.x; a0 = a0 > 0.f ? a0 : NEG_SLOPE * a0;
        float a1 = el4.y + er4.y; a1 = a1 > 0.f ? a1 : NEG_SLOPE * a1;
        float a2 = el4.z + er4.z; a2 = a2 > 0.f ? a2 : NEG_SLOPE * a2;
        float a3 = el4.w + er4.w; a3 = a3 > 0.f ? a3 : NEG_SLOPE * a3;
        mx0 = fmaxf(mx0, a0); mx1 = fmaxf(mx1, a1);
        mx2 = fmaxf(mx2, a2); mx3 = fmaxf(mx3, a3);
    }
    for (int d = 1; d < 64; d <<= 1) {
        mx0 = fmaxf(mx0, __shfl_xor(mx0, d));
        mx1 = fmaxf(mx1, __shfl_xor(mx1, d));
        mx2 = fmaxf(mx2, __shfl_xor(mx2, d));
        mx3 = fmaxf(mx3, __shfl_xor(mx3, d));
    }

    // pass 2: unnormalized weighted accumulation; lane owns cols lane*4..+3
    float acc0 = 0.f, acc1 = 0.f, acc2 = 0.f, acc3 = 0.f;
    float ds0 = 0.f, ds1 = 0.f, ds2 = 0.f, ds3 = 0.f;
    for (int base = beg; base < end; base += 64) {
        int i = base + lane;
        int cnt = end - base; if (cnt > 64) cnt = 64;
        int c = 0;
        float w0 = 0.f, w1 = 0.f, w2 = 0.f, w3 = 0.f;
        if (i < end) {
            c = ebuf[i];
            float4 er4 = *(const float4*)&er[(size_t)c * 4];
            float a0 = el4.x + er4.x; a0 = a0 > 0.f ? a0 : NEG_SLOPE * a0;
            float a1 = el4.y + er4.y; a1 = a1 > 0.f ? a1 : NEG_SLOPE * a1;
            float a2 = el4.z + er4.z; a2 = a2 > 0.f ? a2 : NEG_SLOPE * a2;
            float a3 = el4.w + er4.w; a3 = a3 > 0.f ? a3 : NEG_SLOPE * a3;
            w0 = __expf(a0 - mx0); w1 = __expf(a1 - mx1);
            w2 = __expf(a2 - mx2); w3 = __expf(a3 - mx3);
            ds0 += w0; ds1 += w1; ds2 += w2; ds3 += w3;
        }
        for (int j = 0; j < cnt; ++j) {
            int cc = __shfl(c, j);
            float vw0 = __shfl(w0, j);
            float vw1 = __shfl(w1, j);
            float vw2 = __shfl(w2, j);
            float vw3 = __shfl(w3, j);
            uint2 p = *(const uint2*)(Zp + (size_t)cc * C_TOT + lane * 4);
            float z0 = __uint_as_float(p.x << 16);
            float z1 = __uint_as_float(p.x & 0xFFFF0000u);
            float z2 = __uint_as_float(p.y << 16);
            float z3 = __uint_as_float(p.y & 0xFFFF0000u);
            acc0 += vw0 * z0; acc1 += vw1 * z1;
            acc2 += vw2 * z2; acc3 += vw3 * z3;
        }
    }
    for (int d = 1; d < 64; d <<= 1) {
        ds0 += __shfl_xor(ds0, d); ds1 += __shfl_xor(ds1, d);
        ds2 += __shfl_xor(ds2, d); ds3 += __shfl_xor(ds3, d);
    }
    float i0 = ds0 > 0.f ? 1.f / ds0 : 1.f;
    float i1 = ds1 > 0.f ? 1.f / ds1 : 1.f;
    float i2 = ds2 > 0.f ? 1.f / ds2 : 1.f;
    float i3 = ds3 > 0.f ? 1.f / ds3 : 1.f;
    float4 o;
    o.x = acc0 * i0; o.y = acc1 * i1; o.z = acc2 * i2; o.w = acc3 * i3;
    *(float4*)&out[(size_t)n * C_TOT + lane * 4] = o;
}

extern "C" void kernel_launch(void* const* d_in, const int* in_sizes, int n_in,
                              void* d_out, int out_size, void* d_ws, size_t ws_size,
                              hipStream_t stream)
{
    const float* Z   = (const float*)d_in[0];
    const int*   row = (const int*)d_in[1];
    const int*   col = (const int*)d_in[2];
    const float* W   = (const float*)d_in[3];
    const float* b   = (const float*)d_in[4];
    const float* a_l = (const float*)d_in[5];
    const float* a_r = (const float*)d_in[6];
    float* out = (float*)d_out;
    const int N = in_sizes[0] / IN_F;
    const int E = in_sizes[1];

    // workspace layout (~87 MB)
    char* ws = (char*)d_ws;
    size_t o = 0;
    auto alloc = [&](size_t bytes) -> void* {
        void* p = ws + o;
        o = (o + bytes + 255) & ~(size_t)255;
        return p;
    };
    ushort* Zb  = (ushort*)alloc((size_t)N * IN_F * 2);
    ushort* Wb  = (ushort*)alloc((size_t)C_TOT * IN_F * 2);
    ushort* Zp  = (ushort*)alloc((size_t)N * C_TOT * 2);
    float*  el  = (float*)alloc((size_t)N * 4 * 4);
    float*  er  = (float*)alloc((size_t)N * 4 * 4);
    int*    off = (int*)alloc((size_t)(N + 1) * 4);
    int*    cur = (int*)alloc((size_t)N * 4);
    int*    ebuf= (int*)alloc((size_t)E * 4);

    // bf16 conversions
    cvt_kernel<<<2048, 256, 0, stream>>>(Z, Zb, N * IN_F / 4);
    cvt_kernel<<<32, 256, 0, stream>>>(W, Wb, C_TOT * IN_F / 4);

    // CSR build (by destination = row)
    hipMemsetAsync(cur, 0, (size_t)N * 4, stream);
    hist_kernel<<<(E + 255) / 256, 256, 0, stream>>>(row, cur, E);
    scan_kernel<<<1, 1024, 0, stream>>>(cur, off, N);
    hipMemcpyAsync(cur, off, (size_t)N * 4, hipMemcpyDeviceToDevice, stream);
    scatter_kernel<<<(E + 255) / 256, 256, 0, stream>>>(row, col, cur, ebuf, E);

    // projection + fused logits
    gemm_mfma_kernel<<<(N + 63) / 64, 256, 0, stream>>>(Zb, Wb, b, a_l, a_r,
                                                        Zp, el, er, N);

    // fused softmax + aggregation
    node_kernel<<<(N + 3) / 4, 256, 0, stream>>>(off, ebuf, el, er, Zp, out, N);
}

// Round 3
// 456.338 us; speedup vs baseline: 2.0233x; 1.2967x over previous
//
#include <hip/hip_runtime.h>
#include <math.h>

#define IN_F 128
#define C_TOT 256   // OUT*H
#define NEG_SLOPE 0.2f

typedef __attribute__((ext_vector_type(8))) short short8;
typedef __attribute__((ext_vector_type(4))) float f32x4;

static __device__ __forceinline__ ushort f2bf(float f) {
    unsigned u = __float_as_uint(f);
    unsigned r = (u + 0x7FFF + ((u >> 16) & 1)) >> 16;   // RNE
    return (ushort)r;
}
static __device__ __forceinline__ float bf2f_lo(unsigned w) { return __uint_as_float(w << 16); }
static __device__ __forceinline__ float bf2f_hi(unsigned w) { return __uint_as_float(w & 0xFFFF0000u); }

// ---------------- f32 -> bf16 conversion ----------------
__global__ __launch_bounds__(256) void cvt_kernel(const float* __restrict__ src,
                                                  ushort* __restrict__ dst, int n4)
{
    int i = blockIdx.x * blockDim.x + threadIdx.x;
    int stride = gridDim.x * blockDim.x;
    for (; i < n4; i += stride) {
        float4 v = *(const float4*)&src[(size_t)i * 4];
        ushort4 o;
        o.x = f2bf(v.x); o.y = f2bf(v.y); o.z = f2bf(v.z); o.w = f2bf(v.w);
        *(ushort4*)&dst[(size_t)i * 4] = o;
    }
}

// ---------------- MFMA GEMM: Zp = Z @ W^T + b (bf16), fused e_l/e_r --------
__global__ __launch_bounds__(256) void gemm_mfma_kernel(
    const ushort* __restrict__ Zb, const ushort* __restrict__ Wb,
    const float* __restrict__ bias, const float* __restrict__ a_l,
    const float* __restrict__ a_r, ushort* __restrict__ Zp,
    float* __restrict__ el, float* __restrict__ er, int N)
{
    const int wave = threadIdx.x >> 6, lane = threadIdx.x & 63;
    const int lr = lane & 15, lq = lane >> 4;
    const int row0 = (blockIdx.x * 4 + wave) * 16;
    if (row0 >= N) return;

    short8 afrag[4];
    const bool rowok = (row0 + lr) < N;
    const short* zrow = (const short*)Zb + (size_t)(row0 + lr) * IN_F + lq * 8;
#pragma unroll
    for (int ks = 0; ks < 4; ++ks)
        afrag[ks] = rowok ? *(const short8*)(zrow + ks * 32) : (short8)0;

    f32x4 acc[16];
#pragma unroll
    for (int ct = 0; ct < 16; ++ct) acc[ct] = (f32x4)0.f;

#pragma unroll
    for (int ks = 0; ks < 4; ++ks) {
#pragma unroll
        for (int ct = 0; ct < 16; ++ct) {
            short8 bfrag = *(const short8*)((const short*)Wb +
                           (size_t)(ct * 16 + lr) * IN_F + ks * 32 + lq * 8);
            acc[ct] = __builtin_amdgcn_mfma_f32_16x16x32_bf16(afrag[ks], bfrag, acc[ct], 0, 0, 0);
        }
    }

    float elp[4] = {0.f, 0.f, 0.f, 0.f}, erp[4] = {0.f, 0.f, 0.f, 0.f};
#pragma unroll
    for (int ct = 0; ct < 16; ++ct) {
        const int col = ct * 16 + lr;
        const float bb = bias[col];
        const float al = a_l[col];
        const float ar = a_r[col];
#pragma unroll
        for (int r = 0; r < 4; ++r) {
            const int row = row0 + lq * 4 + r;
            float v = acc[ct][r] + bb;
            if (row < N) Zp[(size_t)row * C_TOT + col] = f2bf(v);
            elp[r] += v * al;
            erp[r] += v * ar;
        }
    }
#pragma unroll
    for (int r = 0; r < 4; ++r) {
        elp[r] += __shfl_xor(elp[r], 4); elp[r] += __shfl_xor(elp[r], 8);
        erp[r] += __shfl_xor(erp[r], 4); erp[r] += __shfl_xor(erp[r], 8);
    }
    if (lr < 4) {
#pragma unroll
        for (int r = 0; r < 4; ++r) {
            const int row = row0 + lq * 4 + r;
            if (row < N) {
                el[row * 4 + lr] = elp[r];
                er[row * 4 + lr] = erp[r];
            }
        }
    }
}

// ---------------- CSR build ----------------
__global__ void hist_kernel(const int* __restrict__ row, int* __restrict__ cnt, int E)
{
    int e = blockIdx.x * blockDim.x + threadIdx.x;
    if (e < E) atomicAdd(&cnt[row[e]], 1);
}

// phase A: per-block (1024 elems) sums
__global__ __launch_bounds__(256) void scan_partial_kernel(
    const int* __restrict__ cnt, int* __restrict__ partial, int N)
{
    __shared__ int red[256];
    const int t = threadIdx.x;
    const int base = blockIdx.x * 1024 + t * 4;
    int4 v = make_int4(0, 0, 0, 0);
    int rem = N - base;
    if (rem >= 4) v = *(const int4*)&cnt[base];
    else if (rem > 0) {
        v.x = cnt[base];
        if (rem > 1) v.y = cnt[base + 1];
        if (rem > 2) v.z = cnt[base + 2];
    }
    red[t] = v.x + v.y + v.z + v.w;
    __syncthreads();
    for (int d = 128; d > 0; d >>= 1) {
        if (t < d) red[t] += red[t + d];
        __syncthreads();
    }
    if (t == 0) partial[blockIdx.x] = red[0];
}

// phase B: exclusive scan of <=256 partials, single block
__global__ __launch_bounds__(256) void scan_small_kernel(int* __restrict__ partial, int B)
{
    __shared__ int s[256];
    const int t = threadIdx.x;
    int own = (t < B) ? partial[t] : 0;
    s[t] = own;
    __syncthreads();
    for (int d = 1; d < 256; d <<= 1) {
        int v = (t >= d) ? s[t - d] : 0;
        __syncthreads();
        s[t] += v;
        __syncthreads();
    }
    if (t < B) partial[t] = s[t] - own;   // exclusive
}

// phase C: final offsets, writes both off[] and cur[]
__global__ __launch_bounds__(256) void scan_final_kernel(
    const int* __restrict__ cnt, const int* __restrict__ partial,
    int* __restrict__ off, int* __restrict__ cur, int N, int E)
{
    __shared__ int red[256];
    const int t = threadIdx.x;
    const int base = blockIdx.x * 1024 + t * 4;
    int4 v = make_int4(0, 0, 0, 0);
    int rem = N - base;
    if (rem >= 4) v = *(const int4*)&cnt[base];
    else if (rem > 0) {
        v.x = cnt[base];
        if (rem > 1) v.y = cnt[base + 1];
        if (rem > 2) v.z = cnt[base + 2];
    }
    const int s = v.x + v.y + v.z + v.w;
    red[t] = s;
    __syncthreads();
    for (int d = 1; d < 256; d <<= 1) {
        int val = (t >= d) ? red[t - d] : 0;
        __syncthreads();
        red[t] += val;
        __syncthreads();
    }
    int run = partial[blockIdx.x] + red[t] - s;   // block prefix + exclusive within block
    if (base < N)     { off[base] = run;     cur[base] = run; }     run += v.x;
    if (base + 1 < N) { off[base + 1] = run; cur[base + 1] = run; } run += v.y;
    if (base + 2 < N) { off[base + 2] = run; cur[base + 2] = run; } run += v.z;
    if (base + 3 < N) { off[base + 3] = run; cur[base + 3] = run; }
    if (blockIdx.x == 0 && t == 0) off[N] = E;
}

__global__ void scatter_kernel(const int* __restrict__ row, const int* __restrict__ col,
                               int* __restrict__ cur, int* __restrict__ ebuf, int E)
{
    int e = blockIdx.x * blockDim.x + threadIdx.x;
    if (e < E) {
        int r = row[e];
        int pos = atomicAdd(&cur[r], 1);
        ebuf[pos] = col[e];
    }
}

// ---------------- fused segment softmax + aggregation ----------------
// Pass 2 layout: 4 subgroups of 16 lanes; subgroup handles one edge per step
// (4 edges/wave-step), lane owns 16 feature cols (fl*16..+15). All subgroup
// loads are same-address (HW broadcast) or coalesced 512B rows. 2-deep
// software pipeline (8 edges in flight).
__global__ __launch_bounds__(256) void node_kernel(
    const int* __restrict__ off, const int* __restrict__ ebuf,
    const float* __restrict__ el, const float* __restrict__ er,
    const ushort* __restrict__ Zp, float* __restrict__ out, int N)
{
    const int wave = threadIdx.x >> 6, lane = threadIdx.x & 63;
    const int n = blockIdx.x * 4 + wave;
    if (n >= N) return;
    const int beg = off[n], end = off[n + 1];
    const float4 el4 = *(const float4*)&el[(size_t)n * 4];

    // ---- pass 1: exact segment max per head (lane-per-edge) ----
    float mx0 = -INFINITY, mx1 = -INFINITY, mx2 = -INFINITY, mx3 = -INFINITY;
    for (int i = beg + lane; i < end; i += 64) {
        int c = ebuf[i];
        float4 er4 = *(const float4*)&er[(size_t)c * 4];
        float a0 = el4.x + er4.x; a0 = a0 > 0.f ? a0 : NEG_SLOPE * a0;
        float a1 = el4.y + er4.y; a1 = a1 > 0.f ? a1 : NEG_SLOPE * a1;
        float a2 = el4.z + er4.z; a2 = a2 > 0.f ? a2 : NEG_SLOPE * a2;
        float a3 = el4.w + er4.w; a3 = a3 > 0.f ? a3 : NEG_SLOPE * a3;
        mx0 = fmaxf(mx0, a0); mx1 = fmaxf(mx1, a1);
        mx2 = fmaxf(mx2, a2); mx3 = fmaxf(mx3, a3);
    }
    for (int d = 1; d < 64; d <<= 1) {
        mx0 = fmaxf(mx0, __shfl_xor(mx0, d));
        mx1 = fmaxf(mx1, __shfl_xor(mx1, d));
        mx2 = fmaxf(mx2, __shfl_xor(mx2, d));
        mx3 = fmaxf(mx3, __shfl_xor(mx3, d));
    }

    // ---- pass 2 ----
    const int sub = lane >> 4, fl = lane & 15;
    float acc[16];
#pragma unroll
    for (int k = 0; k < 16; ++k) acc[k] = 0.f;
    float ds0 = 0.f, ds1 = 0.f, ds2 = 0.f, ds3 = 0.f;

    struct Stage { float4 e4; uint4 a, b; float vm; };
#define LOADE(ii, S) do {                                                     \
        bool _v = (ii) < end;                                                 \
        int _c = _v ? ebuf[(ii)] : 0;                                         \
        (S).vm = _v ? 1.f : 0.f;                                              \
        (S).e4 = *(const float4*)&er[(size_t)_c * 4];                         \
        const ushort* _zr = Zp + (size_t)_c * C_TOT + fl * 16;                \
        (S).a = *(const uint4*)_zr;                                           \
        (S).b = *(const uint4*)(_zr + 8);                                     \
    } while (0)

#define STEP(S) do {                                                          \
        float t0 = el4.x + (S).e4.x; t0 = t0 > 0.f ? t0 : NEG_SLOPE * t0;     \
        float t1 = el4.y + (S).e4.y; t1 = t1 > 0.f ? t1 : NEG_SLOPE * t1;     \
        float t2 = el4.z + (S).e4.z; t2 = t2 > 0.f ? t2 : NEG_SLOPE * t2;     \
        float t3 = el4.w + (S).e4.w; t3 = t3 > 0.f ? t3 : NEG_SLOPE * t3;     \
        float w0 = (S).vm * __expf(t0 - mx0);                                 \
        float w1 = (S).vm * __expf(t1 - mx1);                                 \
        float w2 = (S).vm * __expf(t2 - mx2);                                 \
        float w3 = (S).vm * __expf(t3 - mx3);                                 \
        ds0 += w0; ds1 += w1; ds2 += w2; ds3 += w3;                           \
        unsigned pw[8] = {(S).a.x, (S).a.y, (S).a.z, (S).a.w,                 \
                          (S).b.x, (S).b.y, (S).b.z, (S).b.w};                \
        _Pragma("unroll")                                                     \
        for (int wd = 0; wd < 8; ++wd) {                                      \
            int k0 = wd * 2;                                                  \
            float wl = (k0 & 2) ? ((k0 & 1) ? w3 : w2) : ((k0 & 1) ? w1 : w0);\
            float wh = ((k0+1) & 2) ? (((k0+1) & 1) ? w3 : w2)                \
                                    : (((k0+1) & 1) ? w1 : w0);               \
            acc[k0]     += wl * bf2f_lo(pw[wd]);                              \
            acc[k0 + 1] += wh * bf2f_hi(pw[wd]);                              \
        }                                                                     \
    } while (0)

    const int deg = end - beg;
    const int nc = (deg + 3) >> 2;   // 4-edge chunks
    int ii = beg + sub;
    Stage S0, S1, S2, S3;
    LOADE(ii, S0);
    LOADE(ii + 4, S1);
    for (int t = 0; t < nc; t += 2) {
        LOADE(ii + 8, S2);
        STEP(S0);
        LOADE(ii + 12, S3);
        if (t + 1 < nc) STEP(S1);
        S0 = S2; S1 = S3; ii += 8;
    }
#undef LOADE
#undef STEP

    // reduce across the 4 subgroups (lane-bit 4 and 5)
#pragma unroll
    for (int k = 0; k < 16; ++k) {
        acc[k] += __shfl_xor(acc[k], 16);
        acc[k] += __shfl_xor(acc[k], 32);
    }
    ds0 += __shfl_xor(ds0, 16); ds0 += __shfl_xor(ds0, 32);
    ds1 += __shfl_xor(ds1, 16); ds1 += __shfl_xor(ds1, 32);
    ds2 += __shfl_xor(ds2, 16); ds2 += __shfl_xor(ds2, 32);
    ds3 += __shfl_xor(ds3, 16); ds3 += __shfl_xor(ds3, 32);

    if (sub == 0) {
        float inv[4];
        inv[0] = ds0 > 0.f ? 1.f / ds0 : 1.f;
        inv[1] = ds1 > 0.f ? 1.f / ds1 : 1.f;
        inv[2] = ds2 > 0.f ? 1.f / ds2 : 1.f;
        inv[3] = ds3 > 0.f ? 1.f / ds3 : 1.f;
        float* orow = out + (size_t)n * C_TOT + fl * 16;
#pragma unroll
        for (int g = 0; g < 4; ++g) {
            float4 o;
            o.x = acc[g * 4 + 0] * inv[0];
            o.y = acc[g * 4 + 1] * inv[1];
            o.z = acc[g * 4 + 2] * inv[2];
            o.w = acc[g * 4 + 3] * inv[3];
            *(float4*)(orow + g * 4) = o;
        }
    }
}

extern "C" void kernel_launch(void* const* d_in, const int* in_sizes, int n_in,
                              void* d_out, int out_size, void* d_ws, size_t ws_size,
                              hipStream_t stream)
{
    const float* Z   = (const float*)d_in[0];
    const int*   row = (const int*)d_in[1];
    const int*   col = (const int*)d_in[2];
    const float* W   = (const float*)d_in[3];
    const float* b   = (const float*)d_in[4];
    const float* a_l = (const float*)d_in[5];
    const float* a_r = (const float*)d_in[6];
    float* out = (float*)d_out;
    const int N = in_sizes[0] / IN_F;
    const int E = in_sizes[1];

    char* ws = (char*)d_ws;
    size_t o = 0;
    auto alloc = [&](size_t bytes) -> void* {
        void* p = ws + o;
        o = (o + bytes + 255) & ~(size_t)255;
        return p;
    };
    ushort* Zb   = (ushort*)alloc((size_t)N * IN_F * 2);
    ushort* Wb   = (ushort*)alloc((size_t)C_TOT * IN_F * 2);
    ushort* Zp   = (ushort*)alloc((size_t)N * C_TOT * 2);
    float*  el   = (float*)alloc((size_t)N * 4 * 4);
    float*  er   = (float*)alloc((size_t)N * 4 * 4);
    int*    offs = (int*)alloc((size_t)(N + 1) * 4);
    int*    cnt  = (int*)alloc((size_t)N * 4);
    int*    cur  = (int*)alloc((size_t)N * 4);
    int*    part = (int*)alloc(256 * 4);
    int*    ebuf = (int*)alloc((size_t)E * 4);

    const int nScanBlocks = (N + 1023) / 1024;

    // bf16 conversions
    cvt_kernel<<<2048, 256, 0, stream>>>(Z, Zb, N * IN_F / 4);
    cvt_kernel<<<32, 256, 0, stream>>>(W, Wb, C_TOT * IN_F / 4);

    // CSR build (group by destination = row)
    hipMemsetAsync(cnt, 0, (size_t)N * 4, stream);
    hist_kernel<<<(E + 255) / 256, 256, 0, stream>>>(row, cnt, E);
    scan_partial_kernel<<<nScanBlocks, 256, 0, stream>>>(cnt, part, N);
    scan_small_kernel<<<1, 256, 0, stream>>>(part, nScanBlocks);
    scan_final_kernel<<<nScanBlocks, 256, 0, stream>>>(cnt, part, offs, cur, N, E);
    scatter_kernel<<<(E + 255) / 256, 256, 0, stream>>>(row, col, cur, ebuf, E);

    // projection + fused logits
    gemm_mfma_kernel<<<(N + 63) / 64, 256, 0, stream>>>(Zb, Wb, b, a_l, a_r,
                                                        Zp, el, er, N);

    // fused softmax + aggregation
    node_kernel<<<(N + 3) / 4, 256, 0, stream>>>(offs, ebuf, el, er, Zp, out, N);
}

// Round 4
// 434.207 us; speedup vs baseline: 2.1264x; 1.0510x over previous
//
#include <hip/hip_runtime.h>
#include <math.h>

#define IN_F 128
#define C_TOT 256   // OUT*H
#define NEG_SLOPE 0.2f

typedef __attribute__((ext_vector_type(8))) short short8;
typedef __attribute__((ext_vector_type(4))) float f32x4;

static __device__ __forceinline__ ushort f2bf(float f) {
    unsigned u = __float_as_uint(f);
    unsigned r = (u + 0x7FFF + ((u >> 16) & 1)) >> 16;   // RNE
    return (ushort)r;
}
static __device__ __forceinline__ float bf2f_lo(unsigned w) { return __uint_as_float(w << 16); }
static __device__ __forceinline__ float bf2f_hi(unsigned w) { return __uint_as_float(w & 0xFFFF0000u); }

// ---------------- f32 -> bf16 conversion ----------------
__global__ __launch_bounds__(256) void cvt_kernel(const float* __restrict__ src,
                                                  ushort* __restrict__ dst, int n4)
{
    int i = blockIdx.x * blockDim.x + threadIdx.x;
    int stride = gridDim.x * blockDim.x;
    for (; i < n4; i += stride) {
        float4 v = *(const float4*)&src[(size_t)i * 4];
        ushort4 o;
        o.x = f2bf(v.x); o.y = f2bf(v.y); o.z = f2bf(v.z); o.w = f2bf(v.w);
        *(ushort4*)&dst[(size_t)i * 4] = o;
    }
}

// ---------------- MFMA GEMM: Zp = Z @ W^T + b (bf16), fused e_l/e_r --------
__global__ __launch_bounds__(256) void gemm_mfma_kernel(
    const ushort* __restrict__ Zb, const ushort* __restrict__ Wb,
    const float* __restrict__ bias, const float* __restrict__ a_l,
    const float* __restrict__ a_r, ushort* __restrict__ Zp,
    float* __restrict__ el, float* __restrict__ er, int N)
{
    const int wave = threadIdx.x >> 6, lane = threadIdx.x & 63;
    const int lr = lane & 15, lq = lane >> 4;
    const int row0 = (blockIdx.x * 4 + wave) * 16;
    if (row0 >= N) return;

    short8 afrag[4];
    const bool rowok = (row0 + lr) < N;
    const short* zrow = (const short*)Zb + (size_t)(row0 + lr) * IN_F + lq * 8;
#pragma unroll
    for (int ks = 0; ks < 4; ++ks)
        afrag[ks] = rowok ? *(const short8*)(zrow + ks * 32) : (short8)0;

    f32x4 acc[16];
#pragma unroll
    for (int ct = 0; ct < 16; ++ct) acc[ct] = (f32x4)0.f;

#pragma unroll
    for (int ks = 0; ks < 4; ++ks) {
#pragma unroll
        for (int ct = 0; ct < 16; ++ct) {
            short8 bfrag = *(const short8*)((const short*)Wb +
                           (size_t)(ct * 16 + lr) * IN_F + ks * 32 + lq * 8);
            acc[ct] = __builtin_amdgcn_mfma_f32_16x16x32_bf16(afrag[ks], bfrag, acc[ct], 0, 0, 0);
        }
    }

    float elp[4] = {0.f, 0.f, 0.f, 0.f}, erp[4] = {0.f, 0.f, 0.f, 0.f};
#pragma unroll
    for (int ct = 0; ct < 16; ++ct) {
        const int col = ct * 16 + lr;
        const float bb = bias[col];
        const float al = a_l[col];
        const float ar = a_r[col];
#pragma unroll
        for (int r = 0; r < 4; ++r) {
            const int row = row0 + lq * 4 + r;
            float v = acc[ct][r] + bb;
            if (row < N) Zp[(size_t)row * C_TOT + col] = f2bf(v);
            elp[r] += v * al;
            erp[r] += v * ar;
        }
    }
#pragma unroll
    for (int r = 0; r < 4; ++r) {
        elp[r] += __shfl_xor(elp[r], 4); elp[r] += __shfl_xor(elp[r], 8);
        erp[r] += __shfl_xor(erp[r], 4); erp[r] += __shfl_xor(erp[r], 8);
    }
    if (lr < 4) {
#pragma unroll
        for (int r = 0; r < 4; ++r) {
            const int row = row0 + lq * 4 + r;
            if (row < N) {
                el[row * 4 + lr] = elp[r];
                er[row * 4 + lr] = erp[r];
            }
        }
    }
}

// ---------------- CSR build ----------------
__global__ void hist_kernel(const int* __restrict__ row, int* __restrict__ cnt, int E)
{
    int e = blockIdx.x * blockDim.x + threadIdx.x;
    if (e < E) atomicAdd(&cnt[row[e]], 1);
}

__global__ __launch_bounds__(256) void scan_partial_kernel(
    const int* __restrict__ cnt, int* __restrict__ partial, int N)
{
    __shared__ int red[256];
    const int t = threadIdx.x;
    const int base = blockIdx.x * 1024 + t * 4;
    int4 v = make_int4(0, 0, 0, 0);
    int rem = N - base;
    if (rem >= 4) v = *(const int4*)&cnt[base];
    else if (rem > 0) {
        v.x = cnt[base];
        if (rem > 1) v.y = cnt[base + 1];
        if (rem > 2) v.z = cnt[base + 2];
    }
    red[t] = v.x + v.y + v.z + v.w;
    __syncthreads();
    for (int d = 128; d > 0; d >>= 1) {
        if (t < d) red[t] += red[t + d];
        __syncthreads();
    }
    if (t == 0) partial[blockIdx.x] = red[0];
}

__global__ __launch_bounds__(256) void scan_small_kernel(int* __restrict__ partial, int B)
{
    __shared__ int s[256];
    const int t = threadIdx.x;
    int own = (t < B) ? partial[t] : 0;
    s[t] = own;
    __syncthreads();
    for (int d = 1; d < 256; d <<= 1) {
        int v = (t >= d) ? s[t - d] : 0;
        __syncthreads();
        s[t] += v;
        __syncthreads();
    }
    if (t < B) partial[t] = s[t] - own;   // exclusive
}

__global__ __launch_bounds__(256) void scan_final_kernel(
    const int* __restrict__ cnt, const int* __restrict__ partial,
    int* __restrict__ off, int* __restrict__ cur, int N, int E)
{
    __shared__ int red[256];
    const int t = threadIdx.x;
    const int base = blockIdx.x * 1024 + t * 4;
    int4 v = make_int4(0, 0, 0, 0);
    int rem = N - base;
    if (rem >= 4) v = *(const int4*)&cnt[base];
    else if (rem > 0) {
        v.x = cnt[base];
        if (rem > 1) v.y = cnt[base + 1];
        if (rem > 2) v.z = cnt[base + 2];
    }
    const int s = v.x + v.y + v.z + v.w;
    red[t] = s;
    __syncthreads();
    for (int d = 1; d < 256; d <<= 1) {
        int val = (t >= d) ? red[t - d] : 0;
        __syncthreads();
        red[t] += val;
        __syncthreads();
    }
    int run = partial[blockIdx.x] + red[t] - s;
    if (base < N)     { off[base] = run;     cur[base] = run; }     run += v.x;
    if (base + 1 < N) { off[base + 1] = run; cur[base + 1] = run; } run += v.y;
    if (base + 2 < N) { off[base + 2] = run; cur[base + 2] = run; } run += v.z;
    if (base + 3 < N) { off[base + 3] = run; cur[base + 3] = run; }
    if (blockIdx.x == 0 && t == 0) off[N] = E;
}

__global__ void scatter_kernel(const int* __restrict__ row, const int* __restrict__ col,
                               int* __restrict__ cur, int* __restrict__ ebuf, int E)
{
    int e = blockIdx.x * blockDim.x + threadIdx.x;
    if (e < E) {
        int r = row[e];
        int pos = atomicAdd(&cur[r], 1);
        ebuf[pos] = col[e];
    }
}

// ---------------- edge scores: w[e] = exp(leaky(el[n]+er[c])), inv[n] -------
// subgroup of 16 lanes per node; er gather once; exp once per edge (head-par
// across the 4 float lanes of the float4 math, not redundant across lanes).
__global__ __launch_bounds__(256) void score_kernel(
    const int* __restrict__ off, const int* __restrict__ ebuf,
    const float* __restrict__ el, const float* __restrict__ er,
    float* __restrict__ wbuf, float* __restrict__ inv, int N)
{
    const int sub = threadIdx.x >> 4, fl = threadIdx.x & 15;
    const int n = blockIdx.x * 16 + sub;
    if (n >= N) return;
    const int beg = off[n], end = off[n + 1];
    const float4 el4 = *(const float4*)&el[(size_t)n * 4];
    float d0 = 0.f, d1 = 0.f, d2 = 0.f, d3 = 0.f;
    for (int i = beg + fl; i < end; i += 16) {
        int c = ebuf[i];
        float4 e4 = *(const float4*)&er[(size_t)c * 4];
        float a0 = el4.x + e4.x; a0 = a0 > 0.f ? a0 : NEG_SLOPE * a0;
        float a1 = el4.y + e4.y; a1 = a1 > 0.f ? a1 : NEG_SLOPE * a1;
        float a2 = el4.z + e4.z; a2 = a2 > 0.f ? a2 : NEG_SLOPE * a2;
        float a3 = el4.w + e4.w; a3 = a3 > 0.f ? a3 : NEG_SLOPE * a3;
        // no max-shift: |a| ~ O(10) << 88; clamp for absolute safety
        float w0 = __expf(fminf(a0, 60.f));
        float w1 = __expf(fminf(a1, 60.f));
        float w2 = __expf(fminf(a2, 60.f));
        float w3 = __expf(fminf(a3, 60.f));
        d0 += w0; d1 += w1; d2 += w2; d3 += w3;
        *(float4*)&wbuf[(size_t)i * 4] = make_float4(w0, w1, w2, w3);
    }
#pragma unroll
    for (int d = 1; d < 16; d <<= 1) {
        d0 += __shfl_xor(d0, d); d1 += __shfl_xor(d1, d);
        d2 += __shfl_xor(d2, d); d3 += __shfl_xor(d3, d);
    }
    if (fl == 0) {
        float4 iv;
        iv.x = d0 > 0.f ? 1.f / d0 : 1.f;
        iv.y = d1 > 0.f ? 1.f / d1 : 1.f;
        iv.z = d2 > 0.f ? 1.f / d2 : 1.f;
        iv.w = d3 > 0.f ? 1.f / d3 : 1.f;
        *(float4*)&inv[(size_t)n * 4] = iv;
    }
}

// ---------------- aggregation: out[n] = inv[n] * sum_e w[e]*Zp[col_e] -------
// subgroup of 16 lanes per node; lane owns 16 feature cols. 2-deep pipeline.
__global__ __launch_bounds__(256) void agg_kernel(
    const int* __restrict__ off, const int* __restrict__ ebuf,
    const float* __restrict__ wbuf, const ushort* __restrict__ Zp,
    const float* __restrict__ inv, float* __restrict__ out, int N)
{
    const int sub = threadIdx.x >> 4, fl = threadIdx.x & 15;
    const int n = blockIdx.x * 16 + sub;
    if (n >= N) return;
    const int beg = off[n], end = off[n + 1];

    float acc[16];
#pragma unroll
    for (int k = 0; k < 16; ++k) acc[k] = 0.f;

#define FMA16(A, B, W) do {                                                   \
        unsigned pw[8] = {(A).x, (A).y, (A).z, (A).w,                         \
                          (B).x, (B).y, (B).z, (B).w};                        \
        _Pragma("unroll")                                                     \
        for (int wd = 0; wd < 8; ++wd) {                                      \
            int k0 = wd * 2;                                                  \
            float wl = (k0 & 2) ? (W).z : (W).x;                              \
            float wh = (k0 & 2) ? (W).w : (W).y;                              \
            acc[k0]     += wl * bf2f_lo(pw[wd]);                              \
            acc[k0 + 1] += wh * bf2f_hi(pw[wd]);                              \
        }                                                                     \
    } while (0)

    if (end > beg) {
        int i = beg;
        int c0 = ebuf[i];
        float4 w0 = *(const float4*)&wbuf[(size_t)i * 4];
        const ushort* zr0 = Zp + (size_t)c0 * C_TOT + fl * 16;
        uint4 A0 = *(const uint4*)zr0;
        uint4 B0 = *(const uint4*)(zr0 + 8);
        while (true) {
            int j = i + 1;
            bool more = j < end;
            int jj = more ? j : i;
            int c1 = ebuf[jj];
            float4 w1 = *(const float4*)&wbuf[(size_t)jj * 4];
            const ushort* zr1 = Zp + (size_t)c1 * C_TOT + fl * 16;
            uint4 A1 = *(const uint4*)zr1;
            uint4 B1 = *(const uint4*)(zr1 + 8);
            FMA16(A0, B0, w0);
            if (!more) break;
            i = j; w0 = w1; A0 = A1; B0 = B1;
        }
    }
#undef FMA16

    const float4 iv = *(const float4*)&inv[(size_t)n * 4];
    float* orow = out + (size_t)n * C_TOT + fl * 16;
#pragma unroll
    for (int g = 0; g < 4; ++g) {
        float4 o;
        o.x = acc[g * 4 + 0] * iv.x;
        o.y = acc[g * 4 + 1] * iv.y;
        o.z = acc[g * 4 + 2] * iv.z;
        o.w = acc[g * 4 + 3] * iv.w;
        *(float4*)(orow + g * 4) = o;
    }
}

extern "C" void kernel_launch(void* const* d_in, const int* in_sizes, int n_in,
                              void* d_out, int out_size, void* d_ws, size_t ws_size,
                              hipStream_t stream)
{
    const float* Z   = (const float*)d_in[0];
    const int*   row = (const int*)d_in[1];
    const int*   col = (const int*)d_in[2];
    const float* W   = (const float*)d_in[3];
    const float* b   = (const float*)d_in[4];
    const float* a_l = (const float*)d_in[5];
    const float* a_r = (const float*)d_in[6];
    float* out = (float*)d_out;
    const int N = in_sizes[0] / IN_F;
    const int E = in_sizes[1];

    char* ws = (char*)d_ws;
    size_t o = 0;
    auto alloc = [&](size_t bytes) -> void* {
        void* p = ws + o;
        o = (o + bytes + 255) & ~(size_t)255;
        return p;
    };
    ushort* Zb   = (ushort*)alloc((size_t)N * IN_F * 2);
    ushort* Wb   = (ushort*)alloc((size_t)C_TOT * IN_F * 2);
    ushort* Zp   = (ushort*)alloc((size_t)N * C_TOT * 2);
    float*  el   = (float*)alloc((size_t)N * 4 * 4);
    float*  er   = (float*)alloc((size_t)N * 4 * 4);
    float*  inv  = (float*)alloc((size_t)N * 4 * 4);
    int*    offs = (int*)alloc((size_t)(N + 1) * 4);
    int*    cnt  = (int*)alloc((size_t)N * 4);
    int*    cur  = (int*)alloc((size_t)N * 4);
    int*    part = (int*)alloc(256 * 4);
    int*    ebuf = (int*)alloc((size_t)E * 4);
    float*  wbuf = (float*)alloc((size_t)E * 4 * 4);

    const int nScanBlocks = (N + 1023) / 1024;

    cvt_kernel<<<2048, 256, 0, stream>>>(Z, Zb, N * IN_F / 4);
    cvt_kernel<<<32, 256, 0, stream>>>(W, Wb, C_TOT * IN_F / 4);

    hipMemsetAsync(cnt, 0, (size_t)N * 4, stream);
    hist_kernel<<<(E + 255) / 256, 256, 0, stream>>>(row, cnt, E);
    scan_partial_kernel<<<nScanBlocks, 256, 0, stream>>>(cnt, part, N);
    scan_small_kernel<<<1, 256, 0, stream>>>(part, nScanBlocks);
    scan_final_kernel<<<nScanBlocks, 256, 0, stream>>>(cnt, part, offs, cur, N, E);
    scatter_kernel<<<(E + 255) / 256, 256, 0, stream>>>(row, col, cur, ebuf, E);

    gemm_mfma_kernel<<<(N + 63) / 64, 256, 0, stream>>>(Zb, Wb, b, a_l, a_r,
                                                        Zp, el, er, N);

    score_kernel<<<(N + 15) / 16, 256, 0, stream>>>(offs, ebuf, el, er, wbuf, inv, N);
    agg_kernel<<<(N + 15) / 16, 256, 0, stream>>>(offs, ebuf, wbuf, Zp, inv, out, N);
}

// Round 5
// 431.231 us; speedup vs baseline: 2.1411x; 1.0069x over previous
//
#include <hip/hip_runtime.h>
#include <math.h>

#define IN_F 128
#define C_TOT 256   // OUT*H
#define NEG_SLOPE 0.2f

typedef __attribute__((ext_vector_type(8))) short short8;
typedef __attribute__((ext_vector_type(4))) float f32x4;

static __device__ __forceinline__ ushort f2bf(float f) {
    unsigned u = __float_as_uint(f);
    unsigned r = (u + 0x7FFF + ((u >> 16) & 1)) >> 16;   // RNE
    return (ushort)r;
}
static __device__ __forceinline__ float bf2f_lo(unsigned w) { return __uint_as_float(w << 16); }
static __device__ __forceinline__ float bf2f_hi(unsigned w) { return __uint_as_float(w & 0xFFFF0000u); }

// ---------------- f32 -> bf16 conversion (for W only) ----------------
__global__ __launch_bounds__(256) void cvt_kernel(const float* __restrict__ src,
                                                  ushort* __restrict__ dst, int n4)
{
    int i = blockIdx.x * blockDim.x + threadIdx.x;
    int stride = gridDim.x * blockDim.x;
    for (; i < n4; i += stride) {
        float4 v = *(const float4*)&src[(size_t)i * 4];
        ushort4 o;
        o.x = f2bf(v.x); o.y = f2bf(v.y); o.z = f2bf(v.z); o.w = f2bf(v.w);
        *(ushort4*)&dst[(size_t)i * 4] = o;
    }
}

// ---------------- MFMA GEMM: Zp = Z @ W^T + b, fused Z-cvt + e_l/e_r -------
__global__ __launch_bounds__(256) void gemm_mfma_kernel(
    const float* __restrict__ Z, const ushort* __restrict__ Wb,
    const float* __restrict__ bias, const float* __restrict__ a_l,
    const float* __restrict__ a_r, ushort* __restrict__ Zp,
    float* __restrict__ el, float* __restrict__ er, int N)
{
    const int wave = threadIdx.x >> 6, lane = threadIdx.x & 63;
    const int lr = lane & 15, lq = lane >> 4;
    const int row0 = (blockIdx.x * 4 + wave) * 16;
    if (row0 >= N) return;

    short8 afrag[4];
    const bool rowok = (row0 + lr) < N;
    const float* zrow = Z + (size_t)(row0 + lr) * IN_F + lq * 8;
#pragma unroll
    for (int ks = 0; ks < 4; ++ks) {
        short8 f = (short8)0;
        if (rowok) {
            float4 a0 = *(const float4*)(zrow + ks * 32);
            float4 a1 = *(const float4*)(zrow + ks * 32 + 4);
            f[0] = (short)f2bf(a0.x); f[1] = (short)f2bf(a0.y);
            f[2] = (short)f2bf(a0.z); f[3] = (short)f2bf(a0.w);
            f[4] = (short)f2bf(a1.x); f[5] = (short)f2bf(a1.y);
            f[6] = (short)f2bf(a1.z); f[7] = (short)f2bf(a1.w);
        }
        afrag[ks] = f;
    }

    f32x4 acc[16];
#pragma unroll
    for (int ct = 0; ct < 16; ++ct) acc[ct] = (f32x4)0.f;

#pragma unroll
    for (int ks = 0; ks < 4; ++ks) {
#pragma unroll
        for (int ct = 0; ct < 16; ++ct) {
            short8 bfrag = *(const short8*)((const short*)Wb +
                           (size_t)(ct * 16 + lr) * IN_F + ks * 32 + lq * 8);
            acc[ct] = __builtin_amdgcn_mfma_f32_16x16x32_bf16(afrag[ks], bfrag, acc[ct], 0, 0, 0);
        }
    }

    float elp[4] = {0.f, 0.f, 0.f, 0.f}, erp[4] = {0.f, 0.f, 0.f, 0.f};
#pragma unroll
    for (int ct = 0; ct < 16; ++ct) {
        const int col = ct * 16 + lr;
        const float bb = bias[col];
        const float al = a_l[col];
        const float ar = a_r[col];
#pragma unroll
        for (int r = 0; r < 4; ++r) {
            const int row = row0 + lq * 4 + r;
            float v = acc[ct][r] + bb;
            if (row < N) Zp[(size_t)row * C_TOT + col] = f2bf(v);
            elp[r] += v * al;
            erp[r] += v * ar;
        }
    }
#pragma unroll
    for (int r = 0; r < 4; ++r) {
        elp[r] += __shfl_xor(elp[r], 4); elp[r] += __shfl_xor(elp[r], 8);
        erp[r] += __shfl_xor(erp[r], 4); erp[r] += __shfl_xor(erp[r], 8);
    }
    if (lr < 4) {
#pragma unroll
        for (int r = 0; r < 4; ++r) {
            const int row = row0 + lq * 4 + r;
            if (row < N) {
                el[row * 4 + lr] = elp[r];
                er[row * 4 + lr] = erp[r];
            }
        }
    }
}

// ---------------- CSR build ----------------
__global__ void hist_kernel(const int* __restrict__ row, int* __restrict__ cnt, int E)
{
    int e = blockIdx.x * blockDim.x + threadIdx.x;
    if (e < E) atomicAdd(&cnt[row[e]], 1);
}

__global__ __launch_bounds__(256) void scan_partial_kernel(
    const int* __restrict__ cnt, int* __restrict__ partial, int N)
{
    __shared__ int red[256];
    const int t = threadIdx.x;
    const int base = blockIdx.x * 1024 + t * 4;
    int4 v = make_int4(0, 0, 0, 0);
    int rem = N - base;
    if (rem >= 4) v = *(const int4*)&cnt[base];
    else if (rem > 0) {
        v.x = cnt[base];
        if (rem > 1) v.y = cnt[base + 1];
        if (rem > 2) v.z = cnt[base + 2];
    }
    red[t] = v.x + v.y + v.z + v.w;
    __syncthreads();
    for (int d = 128; d > 0; d >>= 1) {
        if (t < d) red[t] += red[t + d];
        __syncthreads();
    }
    if (t == 0) partial[blockIdx.x] = red[0];
}

__global__ __launch_bounds__(256) void scan_small_kernel(int* __restrict__ partial, int B)
{
    __shared__ int s[256];
    const int t = threadIdx.x;
    int own = (t < B) ? partial[t] : 0;
    s[t] = own;
    __syncthreads();
    for (int d = 1; d < 256; d <<= 1) {
        int v = (t >= d) ? s[t - d] : 0;
        __syncthreads();
        s[t] += v;
        __syncthreads();
    }
    if (t < B) partial[t] = s[t] - own;   // exclusive
}

__global__ __launch_bounds__(256) void scan_final_kernel(
    const int* __restrict__ cnt, const int* __restrict__ partial,
    int* __restrict__ off, int* __restrict__ cur, int N, int E)
{
    __shared__ int red[256];
    const int t = threadIdx.x;
    const int base = blockIdx.x * 1024 + t * 4;
    int4 v = make_int4(0, 0, 0, 0);
    int rem = N - base;
    if (rem >= 4) v = *(const int4*)&cnt[base];
    else if (rem > 0) {
        v.x = cnt[base];
        if (rem > 1) v.y = cnt[base + 1];
        if (rem > 2) v.z = cnt[base + 2];
    }
    const int s = v.x + v.y + v.z + v.w;
    red[t] = s;
    __syncthreads();
    for (int d = 1; d < 256; d <<= 1) {
        int val = (t >= d) ? red[t - d] : 0;
        __syncthreads();
        red[t] += val;
        __syncthreads();
    }
    int run = partial[blockIdx.x] + red[t] - s;
    if (base < N)     { off[base] = run;     cur[base] = run; }     run += v.x;
    if (base + 1 < N) { off[base + 1] = run; cur[base + 1] = run; } run += v.y;
    if (base + 2 < N) { off[base + 2] = run; cur[base + 2] = run; } run += v.z;
    if (base + 3 < N) { off[base + 3] = run; cur[base + 3] = run; }
    if (blockIdx.x == 0 && t == 0) off[N] = E;
}

__global__ void scatter_kernel(const int* __restrict__ row, const int* __restrict__ col,
                               int* __restrict__ cur, int* __restrict__ ebuf, int E)
{
    int e = blockIdx.x * blockDim.x + threadIdx.x;
    if (e < E) {
        int r = row[e];
        int pos = atomicAdd(&cur[r], 1);
        ebuf[pos] = col[e];
    }
}

// ---------------- edge scores ----------------
__global__ __launch_bounds__(256) void score_kernel(
    const int* __restrict__ off, const int* __restrict__ ebuf,
    const float* __restrict__ el, const float* __restrict__ er,
    float* __restrict__ wbuf, float* __restrict__ inv, int N)
{
    const int sub = threadIdx.x >> 4, fl = threadIdx.x & 15;
    const int n = blockIdx.x * 16 + sub;
    if (n >= N) return;
    const int beg = off[n], end = off[n + 1];
    const float4 el4 = *(const float4*)&el[(size_t)n * 4];
    float d0 = 0.f, d1 = 0.f, d2 = 0.f, d3 = 0.f;
    for (int i = beg + fl; i < end; i += 16) {
        int c = ebuf[i];
        float4 e4 = *(const float4*)&er[(size_t)c * 4];
        float a0 = el4.x + e4.x; a0 = a0 > 0.f ? a0 : NEG_SLOPE * a0;
        float a1 = el4.y + e4.y; a1 = a1 > 0.f ? a1 : NEG_SLOPE * a1;
        float a2 = el4.z + e4.z; a2 = a2 > 0.f ? a2 : NEG_SLOPE * a2;
        float a3 = el4.w + e4.w; a3 = a3 > 0.f ? a3 : NEG_SLOPE * a3;
        float w0 = __expf(fminf(a0, 60.f));
        float w1 = __expf(fminf(a1, 60.f));
        float w2 = __expf(fminf(a2, 60.f));
        float w3 = __expf(fminf(a3, 60.f));
        d0 += w0; d1 += w1; d2 += w2; d3 += w3;
        *(float4*)&wbuf[(size_t)i * 4] = make_float4(w0, w1, w2, w3);
    }
#pragma unroll
    for (int d = 1; d < 16; d <<= 1) {
        d0 += __shfl_xor(d0, d); d1 += __shfl_xor(d1, d);
        d2 += __shfl_xor(d2, d); d3 += __shfl_xor(d3, d);
    }
    if (fl == 0) {
        float4 iv;
        iv.x = d0 > 0.f ? 1.f / d0 : 1.f;
        iv.y = d1 > 0.f ? 1.f / d1 : 1.f;
        iv.z = d2 > 0.f ? 1.f / d2 : 1.f;
        iv.w = d3 > 0.f ? 1.f / d3 : 1.f;
        *(float4*)&inv[(size_t)n * 4] = iv;
    }
}

// ---------------- aggregation v2: LDS-staged edge metadata ----------------
// 16 subgroups of 16 lanes; one node per subgroup. Every 16 edges: lanes
// cooperatively load (c, w4) coalesced into LDS (double-buffered, stride-17
// padded -> conflict-free). Process phase: broadcast ds_read per edge, then
// independent Zp gathers (16 unrolled chains -> deep MLP).
__global__ __launch_bounds__(256) void agg_kernel(
    const int* __restrict__ off, const int* __restrict__ ebuf,
    const float* __restrict__ wbuf, const ushort* __restrict__ Zp,
    const float* __restrict__ inv, float* __restrict__ out, int N)
{
    __shared__ int    cS[16][2][17];
    __shared__ float4 wS[16][2][17];
    const int tid = threadIdx.x;
    const int sub = tid >> 4, fl = tid & 15;
    const int n = blockIdx.x * 16 + sub;

    int beg = 0, deg = 0;
    if (n < N) { beg = off[n]; deg = off[n + 1] - beg; }
    int nch = (deg + 15) >> 4;
    // wave-level max of chunk count (subgroup-uniform; reduce over lane bits 4,5)
    {
        int m = nch;
        m = max(m, __shfl_xor(m, 16));
        m = max(m, __shfl_xor(m, 32));
        nch = m;
    }

    float acc[16];
#pragma unroll
    for (int k = 0; k < 16; ++k) acc[k] = 0.f;

#define STAGE(CH, BUF) do {                                                   \
        int _o = (CH) * 16 + fl;                                              \
        bool _v = _o < deg;                                                   \
        int _i = beg + _o;                                                    \
        cS[sub][BUF][fl] = _v ? ebuf[_i] : -1;                                \
        wS[sub][BUF][fl] = _v ? *(const float4*)&wbuf[(size_t)_i * 4]         \
                              : make_float4(0.f, 0.f, 0.f, 0.f);              \
    } while (0)

#define PROCESS(BUF) do {                                                     \
        _Pragma("unroll")                                                     \
        for (int j = 0; j < 16; ++j) {                                        \
            int _c = cS[sub][BUF][j];                                         \
            if (_c >= 0) {                                                    \
                float4 _w = wS[sub][BUF][j];                                  \
                const ushort* _zr = Zp + (size_t)_c * C_TOT + fl * 16;        \
                uint4 _A = *(const uint4*)_zr;                                \
                uint4 _B = *(const uint4*)(_zr + 8);                          \
                unsigned _pw[8] = {_A.x, _A.y, _A.z, _A.w,                    \
                                   _B.x, _B.y, _B.z, _B.w};                   \
                _Pragma("unroll")                                             \
                for (int wd = 0; wd < 8; ++wd) {                              \
                    int k0 = wd * 2;                                          \
                    float wl = (k0 & 2) ? _w.z : _w.x;                        \
                    float wh = (k0 & 2) ? _w.w : _w.y;                        \
                    acc[k0]     += wl * bf2f_lo(_pw[wd]);                     \
                    acc[k0 + 1] += wh * bf2f_hi(_pw[wd]);                     \
                }                                                             \
            }                                                                 \
        }                                                                     \
    } while (0)

    if (nch > 0) {
        STAGE(0, 0);
        int buf = 0;
        for (int ch = 0; ch < nch; ++ch) {
            if (ch + 1 < nch) STAGE(ch + 1, buf ^ 1);
            __builtin_amdgcn_wave_barrier();
            PROCESS(buf);
            __builtin_amdgcn_wave_barrier();
            buf ^= 1;
        }
    }
#undef STAGE
#undef PROCESS

    if (n < N) {
        const float4 iv = *(const float4*)&inv[(size_t)n * 4];
        float* orow = out + (size_t)n * C_TOT + fl * 16;
#pragma unroll
        for (int g = 0; g < 4; ++g) {
            float4 o;
            o.x = acc[g * 4 + 0] * iv.x;
            o.y = acc[g * 4 + 1] * iv.y;
            o.z = acc[g * 4 + 2] * iv.z;
            o.w = acc[g * 4 + 3] * iv.w;
            *(float4*)(orow + g * 4) = o;
        }
    }
}

extern "C" void kernel_launch(void* const* d_in, const int* in_sizes, int n_in,
                              void* d_out, int out_size, void* d_ws, size_t ws_size,
                              hipStream_t stream)
{
    const float* Z   = (const float*)d_in[0];
    const int*   row = (const int*)d_in[1];
    const int*   col = (const int*)d_in[2];
    const float* W   = (const float*)d_in[3];
    const float* b   = (const float*)d_in[4];
    const float* a_l = (const float*)d_in[5];
    const float* a_r = (const float*)d_in[6];
    float* out = (float*)d_out;
    const int N = in_sizes[0] / IN_F;
    const int E = in_sizes[1];

    char* ws = (char*)d_ws;
    size_t o = 0;
    auto alloc = [&](size_t bytes) -> void* {
        void* p = ws + o;
        o = (o + bytes + 255) & ~(size_t)255;
        return p;
    };
    ushort* Wb   = (ushort*)alloc((size_t)C_TOT * IN_F * 2);
    ushort* Zp   = (ushort*)alloc((size_t)N * C_TOT * 2);
    float*  el   = (float*)alloc((size_t)N * 4 * 4);
    float*  er   = (float*)alloc((size_t)N * 4 * 4);
    float*  inv  = (float*)alloc((size_t)N * 4 * 4);
    int*    offs = (int*)alloc((size_t)(N + 1) * 4);
    int*    cnt  = (int*)alloc((size_t)N * 4);
    int*    cur  = (int*)alloc((size_t)N * 4);
    int*    part = (int*)alloc(256 * 4);
    int*    ebuf = (int*)alloc((size_t)E * 4);
    float*  wbuf = (float*)alloc((size_t)E * 4 * 4);

    const int nScanBlocks = (N + 1023) / 1024;

    cvt_kernel<<<32, 256, 0, stream>>>(W, Wb, C_TOT * IN_F / 4);

    gemm_mfma_kernel<<<(N + 63) / 64, 256, 0, stream>>>(Z, Wb, b, a_l, a_r,
                                                        Zp, el, er, N);

    hipMemsetAsync(cnt, 0, (size_t)N * 4, stream);
    hist_kernel<<<(E + 255) / 256, 256, 0, stream>>>(row, cnt, E);
    scan_partial_kernel<<<nScanBlocks, 256, 0, stream>>>(cnt, part, N);
    scan_small_kernel<<<1, 256, 0, stream>>>(part, nScanBlocks);
    scan_final_kernel<<<nScanBlocks, 256, 0, stream>>>(cnt, part, offs, cur, N, E);
    scatter_kernel<<<(E + 255) / 256, 256, 0, stream>>>(row, col, cur, ebuf, E);

    score_kernel<<<(N + 15) / 16, 256, 0, stream>>>(offs, ebuf, el, er, wbuf, inv, N);
    agg_kernel<<<(N + 15) / 16, 256, 0, stream>>>(offs, ebuf, wbuf, Zp, inv, out, N);
}